// Round 7
// baseline (876.237 us; speedup 1.0000x reference)
//
#include <hip/hip_runtime.h>
#include <hip/hip_fp16.h>

#define NN 50000
#define NE 1600000
#define F 32
#define T 4
#define FT 8
#define ED 16
#define NLAYERS 5

// ---------------- CSR build (once per call; edge_index constant across layers) ----

__global__ void zero_cnt(int* __restrict__ cnt) {
    int i = blockIdx.x * 256 + threadIdx.x;
    if (i < NN) cnt[i] = 0;
}

__global__ void count_kernel(const int* __restrict__ ei, int* __restrict__ cnt) {
    int e = blockIdx.x * 256 + threadIdx.x;
    if (e >= NE) return;
    atomicAdd(&cnt[ei[NE + e]], 1);
}

// one-block exclusive scan over cnt[NN] -> row_ptr, cursor (1024 threads)
__global__ void scan_kernel(const int* __restrict__ cnt, int* __restrict__ row_ptr,
                            int* __restrict__ cursor) {
    __shared__ int wsum[16];
    __shared__ int carry_s;
    int tid = threadIdx.x;
    int lane = tid & 63, wid = tid >> 6;
    if (tid == 0) carry_s = 0;
    __syncthreads();
    for (int base = 0; base < NN; base += 1024) {
        int i = base + tid;
        int v = (i < NN) ? cnt[i] : 0;
        int s = v;
#pragma unroll
        for (int off = 1; off < 64; off <<= 1) {
            int tt = __shfl_up(s, off, 64);
            if (lane >= off) s += tt;
        }
        __syncthreads();
        if (lane == 63) wsum[wid] = s;
        __syncthreads();
        if (wid == 0 && lane < 16) {
            int w = wsum[lane];
            int ws = w;
#pragma unroll
            for (int off = 1; off < 16; off <<= 1) {
                int tt = __shfl_up(ws, off, 16);
                if (lane >= off) ws += tt;
            }
            wsum[lane] = ws - w;
        }
        __syncthreads();
        int excl = carry_s + wsum[wid] + s - v;
        if (i < NN) { row_ptr[i] = excl; cursor[i] = excl; }
        __syncthreads();
        if (tid == 1023) carry_s += wsum[15] + s;
    }
}

// fused scatter: read eattr SEQUENTIALLY, compute CSR slot p, write src + fp16 eattr.
__global__ void build_kernel(const int* __restrict__ ei,
                             const float* __restrict__ eattr,
                             int* __restrict__ cursor,
                             int* __restrict__ src_s,
                             float4* __restrict__ eh) {   // [NE][2] float4 (=16 half)
    int e = blockIdx.x * 256 + threadIdx.x;
    if (e >= NE) return;
    int src = ei[e];
    int dst = ei[NE + e];
    const float4* eap = (const float4*)(eattr + (size_t)e * ED);
    float4 v0 = eap[0], v1 = eap[1], v2 = eap[2], v3 = eap[3];
    union { __half h[16]; float4 f4[2]; } u;
    u.h[0]  = __float2half(v0.x); u.h[1]  = __float2half(v0.y);
    u.h[2]  = __float2half(v0.z); u.h[3]  = __float2half(v0.w);
    u.h[4]  = __float2half(v1.x); u.h[5]  = __float2half(v1.y);
    u.h[6]  = __float2half(v1.z); u.h[7]  = __float2half(v1.w);
    u.h[8]  = __float2half(v2.x); u.h[9]  = __float2half(v2.y);
    u.h[10] = __float2half(v2.z); u.h[11] = __float2half(v2.w);
    u.h[12] = __float2half(v3.x); u.h[13] = __float2half(v3.y);
    u.h[14] = __float2half(v3.z); u.h[15] = __float2half(v3.w);
    int p = atomicAdd(&cursor[dst], 1);
    src_s[p] = src;
    eh[2 * (size_t)p]     = u.f4[0];
    eh[2 * (size_t)p + 1] = u.f4[1];
}

// ---------------- per-layer kernels ----------------

__device__ __forceinline__ unsigned short f2bf_rne(float v) {
    unsigned u = __float_as_uint(v);
    return (unsigned short)((u + 0x7FFFu + ((u >> 16) & 1u)) >> 16);
}

// b16[n][ch] = bf16(preW_xj . xt)   (layer 0 only; later layers fused in epilogue)
__global__ void node_pre(const float* __restrict__ xin,
                         const float* __restrict__ preW,
                         unsigned short* __restrict__ b16) {
    int idx = blockIdx.x * 256 + threadIdx.x;
    if (idx >= NN * F) return;
    int n = idx >> 5, ch = idx & 31;
    int t = ch >> 3, f = ch & 7;
    const float* xrow = xin + n * F + t * FT;
    const float* wB = preW + (t * 24 + 8) * 8 + f;
    float bv = 0.f;
#pragma unroll
    for (int k = 0; k < 8; k++) bv += xrow[k] * wB[k * 8];
    b16[idx] = f2bf_rne(bv);
}

// one wave per dst node; 32 lanes = channels, 2 halves alternate edges.
// ee computed on the fly: h = b16_in[src] + eattr_h[i] . wc16  (wc16 = eW @ preW_ee).
// Barrier-free; fuses NEXT layer's node_pre into the epilogue, writing b16_out
// (separate buffer -> no intra-dispatch WAR race).
__global__ __launch_bounds__(256) void gather_post(
        const float* __restrict__ xin,
        const unsigned short* __restrict__ b16_in,
        unsigned short* __restrict__ b16_out,  // may be nullptr (last layer)
        const float4* __restrict__ eh,         // [NE][2] fp16 eattr, CSR order
        const int* __restrict__ row_ptr, const int* __restrict__ cnt,
        const int* __restrict__ src_s,
        const float* __restrict__ eW,          // [16,8] this layer
        const float* __restrict__ ebias,       // [8]
        const float* __restrict__ preW,        // [T,24,8]
        const float* __restrict__ preb,        // [T,8]
        const float* __restrict__ postW, const float* __restrict__ postb,
        const float* __restrict__ linW, const float* __restrict__ linb,
        const float* __restrict__ preW_next,   // next layer's [T,24,8] or nullptr
        float* __restrict__ xout) {
    int tid = threadIdx.x;
    int wv = tid >> 6;
    int lane = tid & 63;
    int ch = lane & 31, half = lane >> 5;
    int n = blockIdx.x * 4 + wv;            // NN divisible by 4
    int t = ch >> 3, f = ch & 7;

    // pj[j] = preW_ee[t][j][f];  wc16[k] = sum_j eW[k][j]*pj[j];  c0 = eb . pj
    float pj[8];
#pragma unroll
    for (int j = 0; j < 8; j++) pj[j] = preW[(t * 24 + 16 + j) * 8 + f];
    float wc16[16];
#pragma unroll
    for (int k = 0; k < 16; k++) {
        float s = 0.f;
#pragma unroll
        for (int j = 0; j < 8; j++) s += eW[k * 8 + j] * pj[j];
        wc16[k] = s;
    }
    float c0 = 0.f;
#pragma unroll
    for (int j = 0; j < 8; j++) c0 += ebias[j] * pj[j];

    int rs = row_ptr[n], deg = cnt[n];
    int re = rs + deg;
    float S = 0.f, M = -3.4e38f;
    int i0 = rs + half;

    int s2 = 0;
    float4 l0 = {0,0,0,0}, h0 = {0,0,0,0};
    float4 l1 = {0,0,0,0}, h1 = {0,0,0,0};
    float4 l2 = {0,0,0,0}, h2 = {0,0,0,0};
    unsigned short b0 = 0, b1 = 0;
    if (i0 < re)     { int s0 = src_s[i0];
                       l0 = eh[2*(size_t)i0];     h0 = eh[2*(size_t)i0+1];
                       b0 = b16_in[s0 * F + ch]; }
    if (i0 + 2 < re) { int s1 = src_s[i0 + 2];
                       l1 = eh[2*(size_t)(i0+2)]; h1 = eh[2*(size_t)(i0+2)+1];
                       b1 = b16_in[s1 * F + ch]; }
    if (i0 + 4 < re) { s2 = src_s[i0 + 4];
                       l2 = eh[2*(size_t)(i0+4)]; h2 = eh[2*(size_t)(i0+4)+1]; }

    for (int i = i0; i < re; i += 2) {
        int s3 = s2; float4 l3 = l2, h3 = h2; unsigned short b2 = b1;
        if (i + 6 < re) { s3 = src_s[i + 6];
                          l3 = eh[2*(size_t)(i+6)]; h3 = eh[2*(size_t)(i+6)+1]; }
        if (i + 4 < re) { b2 = b16_in[s2 * F + ch]; }
        union { float4 f4; __half2 hh[4]; } ua, ub;
        ua.f4 = l0; ub.f4 = h0;
        float h = __uint_as_float((unsigned)b0 << 16);
#pragma unroll
        for (int q = 0; q < 4; q++) {
            float2 pa = __half22float2(ua.hh[q]);
            h += pa.x * wc16[2 * q] + pa.y * wc16[2 * q + 1];
        }
#pragma unroll
        for (int q = 0; q < 4; q++) {
            float2 pb = __half22float2(ub.hh[q]);
            h += pb.x * wc16[8 + 2 * q] + pb.y * wc16[8 + 2 * q + 1];
        }
        S += h;
        M = fmaxf(M, h);
        l0 = l1; h0 = h1; l1 = l2; h1 = h2; l2 = l3; h2 = h3;
        b0 = b1; b1 = b2;
        s2 = s3;
    }
    S += __shfl_xor(S, 32, 64);
    M = fmaxf(M, __shfl_xor(M, 32, 64));

    float xv = xin[(size_t)n * F + ch];
    // a_val = preb + c0 + preW_xi . xt  (own node, via shuffles of xv)
    float a_val = preb[t * 8 + f] + c0;
#pragma unroll
    for (int j = 0; j < 8; j++)
        a_val += __shfl(xv, t * 8 + j, 64) * preW[(t * 24 + j) * 8 + f];

    float sum_h, mean_h, max_h;
    if (deg > 0) {
        sum_h = S + (float)deg * a_val;
        mean_h = sum_h / (float)deg;
        max_h = M + a_val;
    } else {
        sum_h = 0.f; mean_h = 0.f; max_h = 0.f;
    }

    // post-MLP per tower: u = postb + [xt|mean|sum|max] @ postW   (via shuffles)
    float u2 = postb[t * 8 + f];
#pragma unroll
    for (int kk = 0; kk < 8; kk++) {
        int sl = t * 8 + kk;
        u2 += __shfl(xv,     sl, 64) * postW[(t * 32 + 0 * 8 + kk) * 8 + f];
        u2 += __shfl(mean_h, sl, 64) * postW[(t * 32 + 1 * 8 + kk) * 8 + f];
        u2 += __shfl(sum_h,  sl, 64) * postW[(t * 32 + 2 * 8 + kk) * 8 + f];
        u2 += __shfl(max_h,  sl, 64) * postW[(t * 32 + 3 * 8 + kk) * 8 + f];
    }
    // final mixing linear + relu
    float y = linb[ch];
#pragma unroll
    for (int k = 0; k < 32; k++)
        y += __shfl(u2, k, 64) * linW[k * 32 + ch];
    y = fmaxf(y, 0.f);
    if (half == 0)
        xout[(size_t)n * F + ch] = y;

    // fused node_pre for next layer -> DIFFERENT buffer (no race)
    if (preW_next) {
        float bn = 0.f;
#pragma unroll
        for (int j = 0; j < 8; j++)
            bn += __shfl(y, t * 8 + j, 64) * preW_next[(t * 24 + 8 + j) * 8 + f];
        if (half == 0)
            b16_out[(size_t)n * F + ch] = f2bf_rne(bn);
    }
}

// ---------------- launch ----------------

extern "C" void kernel_launch(void* const* d_in, const int* in_sizes, int n_in,
                              void* d_out, int out_size, void* d_ws, size_t ws_size,
                              hipStream_t stream) {
    const float* x      = (const float*)d_in[0];
    const int*   ei     = (const int*)d_in[1];
    const float* eattr  = (const float*)d_in[2];
    const float* edge_W = (const float*)d_in[3];
    const float* edge_b = (const float*)d_in[4];
    const float* pre_W  = (const float*)d_in[5];
    const float* pre_b  = (const float*)d_in[6];
    const float* post_W = (const float*)d_in[7];
    const float* post_b = (const float*)d_in[8];
    const float* lin_W  = (const float*)d_in[9];
    const float* lin_b  = (const float*)d_in[10];
    float* out = (float*)d_out;

    const size_t NC = (size_t)NN * F;
    char* p = (char*)d_ws;
    float4* eh    = (float4*)p;        p += sizeof(float4) * 2 * (size_t)NE;  // 51.2 MB
    int* src_s    = (int*)p;           p += sizeof(int) * NE;
    int* cnt      = (int*)p;           p += sizeof(int) * NN;
    int* row_ptr  = (int*)p;           p += sizeof(int) * NN;
    int* cursor   = (int*)p;           p += sizeof(int) * NN;
    unsigned short* b16a = (unsigned short*)p;  p += sizeof(unsigned short) * NC;
    unsigned short* b16b = (unsigned short*)p;  p += sizeof(unsigned short) * NC;
    float* xb0    = (float*)p;         p += sizeof(float) * NC;
    float* xb1    = (float*)p;         p += sizeof(float) * NC;

    dim3 blk(256);
    int gN  = (NN + 255) / 256;
    int gE  = (NE + 255) / 256;
    int gNC = (NN * F + 255) / 256;
    int gG  = NN / 4;

    // CSR build + fp16 eattr permute (once; reused by all 5 layers)
    hipLaunchKernelGGL(zero_cnt,     dim3(gN), blk, 0, stream, cnt);
    hipLaunchKernelGGL(count_kernel, dim3(gE), blk, 0, stream, ei, cnt);
    hipLaunchKernelGGL(scan_kernel,  dim3(1), dim3(1024), 0, stream, cnt, row_ptr, cursor);
    hipLaunchKernelGGL(build_kernel, dim3(gE), blk, 0, stream, ei, eattr,
                       cursor, src_s, eh);

    // layer 0's b16
    hipLaunchKernelGGL(node_pre, dim3(gNC), blk, 0, stream, x, pre_W, b16a);

    const float* xin = x;
    for (int l = 0; l < NLAYERS; l++) {
        const float* eWl = edge_W + (size_t)l * ED * FT;
        const float* ebl = edge_b + (size_t)l * FT;
        const float* pW  = pre_W  + (size_t)l * T * 24 * FT;
        const float* pb  = pre_b  + (size_t)l * T * FT;
        const float* poW = post_W + (size_t)l * T * 32 * FT;
        const float* pob = post_b + (size_t)l * T * FT;
        const float* lW  = lin_W  + (size_t)l * F * F;
        const float* lb  = lin_b  + (size_t)l * F;
        const float* pWn = (l + 1 < NLAYERS) ? (pre_W + (size_t)(l + 1) * T * 24 * FT)
                                             : nullptr;
        float* xout = (l == NLAYERS - 1) ? out : ((l & 1) ? xb1 : xb0);
        const unsigned short* bin  = (l & 1) ? b16b : b16a;
        unsigned short*       bout = (l & 1) ? b16a : b16b;

        hipLaunchKernelGGL(gather_post, dim3(gG), blk, 0, stream,
                           xin, bin, pWn ? bout : nullptr, eh, row_ptr, cnt, src_s,
                           eWl, ebl, pW, pb, poW, pob, lW, lb, pWn, xout);
        xin = xout;
    }
}

// Round 8
// 781.573 us; speedup vs baseline: 1.1211x; 1.1211x over previous
//
#include <hip/hip_runtime.h>
#include <hip/hip_fp16.h>

#define NN 50000
#define NE 1600000
#define F 32
#define T 4
#define FT 8
#define ED 16
#define NLAYERS 5

typedef _Float16 h2 __attribute__((ext_vector_type(2)));

__device__ __forceinline__ float dot2(h2 a, h2 b, float c) {
#if __has_builtin(__builtin_amdgcn_fdot2)
    return __builtin_amdgcn_fdot2(a, b, c, false);
#else
    return c + (float)a.x * (float)b.x + (float)a.y * (float)b.y;
#endif
}

// ---------------- CSR build (once per call; edge_index constant across layers) ----

__global__ void zero_cnt(int* __restrict__ cnt) {
    int i = blockIdx.x * 256 + threadIdx.x;
    if (i < NN) cnt[i] = 0;
}

__global__ void count_kernel(const int* __restrict__ ei, int* __restrict__ cnt) {
    int e = blockIdx.x * 256 + threadIdx.x;
    if (e >= NE) return;
    atomicAdd(&cnt[ei[NE + e]], 1);
}

// one-block exclusive scan over cnt[NN] -> row_ptr, cursor (1024 threads)
__global__ void scan_kernel(const int* __restrict__ cnt, int* __restrict__ row_ptr,
                            int* __restrict__ cursor) {
    __shared__ int wsum[16];
    __shared__ int carry_s;
    int tid = threadIdx.x;
    int lane = tid & 63, wid = tid >> 6;
    if (tid == 0) carry_s = 0;
    __syncthreads();
    for (int base = 0; base < NN; base += 1024) {
        int i = base + tid;
        int v = (i < NN) ? cnt[i] : 0;
        int s = v;
#pragma unroll
        for (int off = 1; off < 64; off <<= 1) {
            int tt = __shfl_up(s, off, 64);
            if (lane >= off) s += tt;
        }
        __syncthreads();
        if (lane == 63) wsum[wid] = s;
        __syncthreads();
        if (wid == 0 && lane < 16) {
            int w = wsum[lane];
            int ws = w;
#pragma unroll
            for (int off = 1; off < 16; off <<= 1) {
                int tt = __shfl_up(ws, off, 16);
                if (lane >= off) ws += tt;
            }
            wsum[lane] = ws - w;
        }
        __syncthreads();
        int excl = carry_s + wsum[wid] + s - v;
        if (i < NN) { row_ptr[i] = excl; cursor[i] = excl; }
        __syncthreads();
        if (tid == 1023) carry_s += wsum[15] + s;
    }
}

// fused scatter: read eattr SEQUENTIALLY, compute CSR slot p, write src + fp16 eattr.
__global__ void build_kernel(const int* __restrict__ ei,
                             const float* __restrict__ eattr,
                             int* __restrict__ cursor,
                             int* __restrict__ src_s,
                             float4* __restrict__ eh) {   // [NE][2] float4 (=16 half)
    int e = blockIdx.x * 256 + threadIdx.x;
    if (e >= NE) return;
    int src = ei[e];
    int dst = ei[NE + e];
    const float4* eap = (const float4*)(eattr + (size_t)e * ED);
    float4 v0 = eap[0], v1 = eap[1], v2 = eap[2], v3 = eap[3];
    union { __half hh[16]; float4 f4[2]; } u;
    u.hh[0]  = __float2half(v0.x); u.hh[1]  = __float2half(v0.y);
    u.hh[2]  = __float2half(v0.z); u.hh[3]  = __float2half(v0.w);
    u.hh[4]  = __float2half(v1.x); u.hh[5]  = __float2half(v1.y);
    u.hh[6]  = __float2half(v1.z); u.hh[7]  = __float2half(v1.w);
    u.hh[8]  = __float2half(v2.x); u.hh[9]  = __float2half(v2.y);
    u.hh[10] = __float2half(v2.z); u.hh[11] = __float2half(v2.w);
    u.hh[12] = __float2half(v3.x); u.hh[13] = __float2half(v3.y);
    u.hh[14] = __float2half(v3.z); u.hh[15] = __float2half(v3.w);
    int p = atomicAdd(&cursor[dst], 1);
    src_s[p] = src;
    eh[2 * (size_t)p]     = u.f4[0];
    eh[2 * (size_t)p + 1] = u.f4[1];
}

// ---------------- per-layer kernels ----------------

__device__ __forceinline__ unsigned short f2bf_rne(float v) {
    unsigned u = __float_as_uint(v);
    return (unsigned short)((u + 0x7FFFu + ((u >> 16) & 1u)) >> 16);
}

// b16[n][ch] = bf16(preW_xj . xt)   (layer 0 only; later layers fused in epilogue)
__global__ void node_pre(const float* __restrict__ xin,
                         const float* __restrict__ preW,
                         unsigned short* __restrict__ b16) {
    int idx = blockIdx.x * 256 + threadIdx.x;
    if (idx >= NN * F) return;
    int n = idx >> 5, ch = idx & 31;
    int t = ch >> 3, f = ch & 7;
    const float* xrow = xin + n * F + t * FT;
    const float* wB = preW + (t * 24 + 8) * 8 + f;
    float bv = 0.f;
#pragma unroll
    for (int k = 0; k < 8; k++) bv += xrow[k] * wB[k * 8];
    b16[idx] = f2bf_rne(bv);
}

// one wave per dst node; 32 lanes = channels, 2 halves alternate edges.
// ee computed on the fly via v_dot2_f32_f16: h = b16_in[src] + sum_q dot2(eh2[q], wch[q]).
// Barrier-free; fuses NEXT layer's node_pre into the epilogue (separate buffer).
__global__ __launch_bounds__(256) void gather_post(
        const float* __restrict__ xin,
        const unsigned short* __restrict__ b16_in,
        unsigned short* __restrict__ b16_out,  // may be nullptr (last layer)
        const float4* __restrict__ eh,         // [NE][2] fp16 eattr, CSR order
        const int* __restrict__ row_ptr, const int* __restrict__ cnt,
        const int* __restrict__ src_s,
        const float* __restrict__ eW,          // [16,8] this layer
        const float* __restrict__ ebias,       // [8]
        const float* __restrict__ preW,        // [T,24,8]
        const float* __restrict__ preb,        // [T,8]
        const float* __restrict__ postW, const float* __restrict__ postb,
        const float* __restrict__ linW, const float* __restrict__ linb,
        const float* __restrict__ preW_next,   // next layer's [T,24,8] or nullptr
        float* __restrict__ xout) {
    int tid = threadIdx.x;
    int wv = tid >> 6;
    int lane = tid & 63;
    int ch = lane & 31, half = lane >> 5;
    int n = blockIdx.x * 4 + wv;            // NN divisible by 4
    int t = ch >> 3, f = ch & 7;

    // pj[j] = preW_ee[t][j][f];  wc[k] = sum_j eW[k][j]*pj[j] -> packed half2 wch[8]
    float pj[8];
#pragma unroll
    for (int j = 0; j < 8; j++) pj[j] = preW[(t * 24 + 16 + j) * 8 + f];
    h2 wch[8];
#pragma unroll
    for (int q = 0; q < 8; q++) {
        float s0 = 0.f, s1 = 0.f;
#pragma unroll
        for (int j = 0; j < 8; j++) {
            s0 += eW[(2 * q) * 8 + j] * pj[j];
            s1 += eW[(2 * q + 1) * 8 + j] * pj[j];
        }
        h2 w; w.x = (_Float16)s0; w.y = (_Float16)s1;
        wch[q] = w;
    }
    float c0 = 0.f;
#pragma unroll
    for (int j = 0; j < 8; j++) c0 += ebias[j] * pj[j];

    int rs = row_ptr[n], deg = cnt[n];
    int re = rs + deg;
    float S = 0.f, M = -3.4e38f;
    int i0 = rs + half;

    // 2-deep pipeline: A = current edge, B = next edge (dist 2)
    int sB = 0;
    float4 lA = {0,0,0,0}, hA = {0,0,0,0}, lB = {0,0,0,0}, hB = {0,0,0,0};
    unsigned short bA = 0, bB = 0;
    if (i0 < re) {
        int sA = src_s[i0];
        lA = eh[2 * (size_t)i0]; hA = eh[2 * (size_t)i0 + 1];
        bA = b16_in[sA * F + ch];
    }
    if (i0 + 2 < re) {
        sB = src_s[i0 + 2];
        lB = eh[2 * (size_t)(i0 + 2)]; hB = eh[2 * (size_t)(i0 + 2) + 1];
    }

    for (int i = i0; i < re; i += 2) {
        // prefetch edge i+4 (stream) and b for edge i+2 (dependent chain dist 1)
        int sC = 0;
        float4 lC = {0,0,0,0}, hC = {0,0,0,0};
        if (i + 4 < re) {
            sC = src_s[i + 4];
            lC = eh[2 * (size_t)(i + 4)]; hC = eh[2 * (size_t)(i + 4) + 1];
        }
        if (i + 2 < re) bB = b16_in[sB * F + ch];
        // compute current edge
        union { float4 f4; h2 p[4]; } ua, ub;
        ua.f4 = lA; ub.f4 = hA;
        float h = __uint_as_float((unsigned)bA << 16);
        h = dot2(ua.p[0], wch[0], h);
        h = dot2(ua.p[1], wch[1], h);
        h = dot2(ua.p[2], wch[2], h);
        h = dot2(ua.p[3], wch[3], h);
        h = dot2(ub.p[0], wch[4], h);
        h = dot2(ub.p[1], wch[5], h);
        h = dot2(ub.p[2], wch[6], h);
        h = dot2(ub.p[3], wch[7], h);
        S += h;
        M = fmaxf(M, h);
        // rotate
        lA = lB; hA = hB; bA = bB;
        lB = lC; hB = hC; sB = sC;
    }
    S += __shfl_xor(S, 32, 64);
    M = fmaxf(M, __shfl_xor(M, 32, 64));

    float xv = xin[(size_t)n * F + ch];
    // a_val = preb + c0 + preW_xi . xt  (own node, via shuffles of xv)
    float a_val = preb[t * 8 + f] + c0;
#pragma unroll
    for (int j = 0; j < 8; j++)
        a_val += __shfl(xv, t * 8 + j, 64) * preW[(t * 24 + j) * 8 + f];

    float sum_h, mean_h, max_h;
    if (deg > 0) {
        sum_h = S + (float)deg * a_val;
        mean_h = sum_h / (float)deg;
        max_h = M + a_val;
    } else {
        sum_h = 0.f; mean_h = 0.f; max_h = 0.f;
    }

    // post-MLP per tower: u = postb + [xt|mean|sum|max] @ postW   (via shuffles)
    float u2 = postb[t * 8 + f];
#pragma unroll
    for (int kk = 0; kk < 8; kk++) {
        int sl = t * 8 + kk;
        u2 += __shfl(xv,     sl, 64) * postW[(t * 32 + 0 * 8 + kk) * 8 + f];
        u2 += __shfl(mean_h, sl, 64) * postW[(t * 32 + 1 * 8 + kk) * 8 + f];
        u2 += __shfl(sum_h,  sl, 64) * postW[(t * 32 + 2 * 8 + kk) * 8 + f];
        u2 += __shfl(max_h,  sl, 64) * postW[(t * 32 + 3 * 8 + kk) * 8 + f];
    }
    // final mixing linear + relu
    float y = linb[ch];
#pragma unroll
    for (int k = 0; k < 32; k++)
        y += __shfl(u2, k, 64) * linW[k * 32 + ch];
    y = fmaxf(y, 0.f);
    if (half == 0)
        xout[(size_t)n * F + ch] = y;

    // fused node_pre for next layer -> DIFFERENT buffer (no race)
    if (preW_next) {
        float bn = 0.f;
#pragma unroll
        for (int j = 0; j < 8; j++)
            bn += __shfl(y, t * 8 + j, 64) * preW_next[(t * 24 + 8 + j) * 8 + f];
        if (half == 0)
            b16_out[(size_t)n * F + ch] = f2bf_rne(bn);
    }
}

// ---------------- launch ----------------

extern "C" void kernel_launch(void* const* d_in, const int* in_sizes, int n_in,
                              void* d_out, int out_size, void* d_ws, size_t ws_size,
                              hipStream_t stream) {
    const float* x      = (const float*)d_in[0];
    const int*   ei     = (const int*)d_in[1];
    const float* eattr  = (const float*)d_in[2];
    const float* edge_W = (const float*)d_in[3];
    const float* edge_b = (const float*)d_in[4];
    const float* pre_W  = (const float*)d_in[5];
    const float* pre_b  = (const float*)d_in[6];
    const float* post_W = (const float*)d_in[7];
    const float* post_b = (const float*)d_in[8];
    const float* lin_W  = (const float*)d_in[9];
    const float* lin_b  = (const float*)d_in[10];
    float* out = (float*)d_out;

    const size_t NC = (size_t)NN * F;
    char* p = (char*)d_ws;
    float4* eh    = (float4*)p;        p += sizeof(float4) * 2 * (size_t)NE;  // 51.2 MB
    int* src_s    = (int*)p;           p += sizeof(int) * NE;
    int* cnt      = (int*)p;           p += sizeof(int) * NN;
    int* row_ptr  = (int*)p;           p += sizeof(int) * NN;
    int* cursor   = (int*)p;           p += sizeof(int) * NN;
    unsigned short* b16a = (unsigned short*)p;  p += sizeof(unsigned short) * NC;
    unsigned short* b16b = (unsigned short*)p;  p += sizeof(unsigned short) * NC;
    float* xb0    = (float*)p;         p += sizeof(float) * NC;
    float* xb1    = (float*)p;         p += sizeof(float) * NC;

    dim3 blk(256);
    int gN  = (NN + 255) / 256;
    int gE  = (NE + 255) / 256;
    int gNC = (NN * F + 255) / 256;
    int gG  = NN / 4;

    // CSR build + fp16 eattr permute (once; reused by all 5 layers)
    hipLaunchKernelGGL(zero_cnt,     dim3(gN), blk, 0, stream, cnt);
    hipLaunchKernelGGL(count_kernel, dim3(gE), blk, 0, stream, ei, cnt);
    hipLaunchKernelGGL(scan_kernel,  dim3(1), dim3(1024), 0, stream, cnt, row_ptr, cursor);
    hipLaunchKernelGGL(build_kernel, dim3(gE), blk, 0, stream, ei, eattr,
                       cursor, src_s, eh);

    // layer 0's b16
    hipLaunchKernelGGL(node_pre, dim3(gNC), blk, 0, stream, x, pre_W, b16a);

    const float* xin = x;
    for (int l = 0; l < NLAYERS; l++) {
        const float* eWl = edge_W + (size_t)l * ED * FT;
        const float* ebl = edge_b + (size_t)l * FT;
        const float* pW  = pre_W  + (size_t)l * T * 24 * FT;
        const float* pb  = pre_b  + (size_t)l * T * FT;
        const float* poW = post_W + (size_t)l * T * 32 * FT;
        const float* pob = post_b + (size_t)l * T * FT;
        const float* lW  = lin_W  + (size_t)l * F * F;
        const float* lb  = lin_b  + (size_t)l * F;
        const float* pWn = (l + 1 < NLAYERS) ? (pre_W + (size_t)(l + 1) * T * 24 * FT)
                                             : nullptr;
        float* xout = (l == NLAYERS - 1) ? out : ((l & 1) ? xb1 : xb0);
        const unsigned short* bin  = (l & 1) ? b16b : b16a;
        unsigned short*       bout = (l & 1) ? b16a : b16b;

        hipLaunchKernelGGL(gather_post, dim3(gG), blk, 0, stream,
                           xin, bin, pWn ? bout : nullptr, eh, row_ptr, cnt, src_s,
                           eWl, ebl, pW, pb, poW, pob, lW, lb, pWn, xout);
        xin = xout;
    }
}

// Round 9
// 768.237 us; speedup vs baseline: 1.1406x; 1.0174x over previous
//
#include <hip/hip_runtime.h>
#include <hip/hip_fp16.h>

#define NN 50000
#define NE 1600000
#define F 32
#define T 4
#define FT 8
#define ED 16
#define NLAYERS 5

typedef _Float16 h2 __attribute__((ext_vector_type(2)));

__device__ __forceinline__ float dot2(h2 a, h2 b, float c) {
#if __has_builtin(__builtin_amdgcn_fdot2)
    return __builtin_amdgcn_fdot2(a, b, c, false);
#else
    return c + (float)a.x * (float)b.x + (float)a.y * (float)b.y;
#endif
}

// ---------------- CSR build (once per call; edge_index constant across layers) ----

__global__ void zero_cnt(int* __restrict__ cnt) {
    int i = blockIdx.x * 256 + threadIdx.x;
    if (i < NN) cnt[i] = 0;
}

__global__ void count_kernel(const int* __restrict__ ei, int* __restrict__ cnt) {
    int e = blockIdx.x * 256 + threadIdx.x;
    if (e >= NE) return;
    atomicAdd(&cnt[ei[NE + e]], 1);
}

// one-block exclusive scan over cnt[NN] -> row_ptr, cursor (1024 threads)
__global__ void scan_kernel(const int* __restrict__ cnt, int* __restrict__ row_ptr,
                            int* __restrict__ cursor) {
    __shared__ int wsum[16];
    __shared__ int carry_s;
    int tid = threadIdx.x;
    int lane = tid & 63, wid = tid >> 6;
    if (tid == 0) carry_s = 0;
    __syncthreads();
    for (int base = 0; base < NN; base += 1024) {
        int i = base + tid;
        int v = (i < NN) ? cnt[i] : 0;
        int s = v;
#pragma unroll
        for (int off = 1; off < 64; off <<= 1) {
            int tt = __shfl_up(s, off, 64);
            if (lane >= off) s += tt;
        }
        __syncthreads();
        if (lane == 63) wsum[wid] = s;
        __syncthreads();
        if (wid == 0 && lane < 16) {
            int w = wsum[lane];
            int ws = w;
#pragma unroll
            for (int off = 1; off < 16; off <<= 1) {
                int tt = __shfl_up(ws, off, 16);
                if (lane >= off) ws += tt;
            }
            wsum[lane] = ws - w;
        }
        __syncthreads();
        int excl = carry_s + wsum[wid] + s - v;
        if (i < NN) { row_ptr[i] = excl; cursor[i] = excl; }
        __syncthreads();
        if (tid == 1023) carry_s += wsum[15] + s;
    }
}

// fused scatter: read eattr SEQUENTIALLY, compute CSR slot p, write src + fp16 eattr.
__global__ void build_kernel(const int* __restrict__ ei,
                             const float* __restrict__ eattr,
                             int* __restrict__ cursor,
                             int* __restrict__ src_s,
                             float4* __restrict__ eh) {   // [NE][2] float4 (=16 half)
    int e = blockIdx.x * 256 + threadIdx.x;
    if (e >= NE) return;
    int src = ei[e];
    int dst = ei[NE + e];
    const float4* eap = (const float4*)(eattr + (size_t)e * ED);
    float4 v0 = eap[0], v1 = eap[1], v2 = eap[2], v3 = eap[3];
    union { __half hh[16]; float4 f4[2]; } u;
    u.hh[0]  = __float2half(v0.x); u.hh[1]  = __float2half(v0.y);
    u.hh[2]  = __float2half(v0.z); u.hh[3]  = __float2half(v0.w);
    u.hh[4]  = __float2half(v1.x); u.hh[5]  = __float2half(v1.y);
    u.hh[6]  = __float2half(v1.z); u.hh[7]  = __float2half(v1.w);
    u.hh[8]  = __float2half(v2.x); u.hh[9]  = __float2half(v2.y);
    u.hh[10] = __float2half(v2.z); u.hh[11] = __float2half(v2.w);
    u.hh[12] = __float2half(v3.x); u.hh[13] = __float2half(v3.y);
    u.hh[14] = __float2half(v3.z); u.hh[15] = __float2half(v3.w);
    int p = atomicAdd(&cursor[dst], 1);
    src_s[p] = src;
    eh[2 * (size_t)p]     = u.f4[0];
    eh[2 * (size_t)p + 1] = u.f4[1];
}

// per-layer constants: wchp[(l*32+ch)] = packed fp16 wc16 (16 halfs = 2 float4);
// abias[l*32+ch] = preb + ebias . preW_ee
__global__ void layer_const(const float* __restrict__ edge_W,  // [L,16,8]
                            const float* __restrict__ edge_b,  // [L,8]
                            const float* __restrict__ pre_W,   // [L,T,24,8]
                            const float* __restrict__ pre_b,   // [L,T,8]
                            float4* __restrict__ wchp,         // [L*32][2]
                            float* __restrict__ abias) {       // [L*32]
    int idx = threadIdx.x;
    if (idx >= NLAYERS * 32) return;
    int l = idx >> 5, ch = idx & 31;
    int t = ch >> 3, f = ch & 7;
    const float* eW = edge_W + (size_t)l * ED * FT;
    const float* eb = edge_b + (size_t)l * FT;
    const float* pW = pre_W + (size_t)l * T * 24 * FT;
    const float* pb = pre_b + (size_t)l * T * FT;
    float pj[8];
#pragma unroll
    for (int j = 0; j < 8; j++) pj[j] = pW[(t * 24 + 16 + j) * 8 + f];
    union { _Float16 hh[16]; float4 f4[2]; } u;
#pragma unroll
    for (int k = 0; k < 16; k++) {
        float s = 0.f;
#pragma unroll
        for (int j = 0; j < 8; j++) s += eW[k * 8 + j] * pj[j];
        u.hh[k] = (_Float16)s;
    }
    float c0 = pb[t * 8 + f];
#pragma unroll
    for (int j = 0; j < 8; j++) c0 += eb[j] * pj[j];
    wchp[2 * idx]     = u.f4[0];
    wchp[2 * idx + 1] = u.f4[1];
    abias[idx] = c0;
}

// ---------------- per-layer kernels ----------------

__device__ __forceinline__ unsigned short f2bf_rne(float v) {
    unsigned u = __float_as_uint(v);
    return (unsigned short)((u + 0x7FFFu + ((u >> 16) & 1u)) >> 16);
}

// b16[n][ch] = bf16(preW_xj . xt)   (layer 0 only; later layers fused in epilogue)
__global__ void node_pre(const float* __restrict__ xin,
                         const float* __restrict__ preW,
                         unsigned short* __restrict__ b16) {
    int idx = blockIdx.x * 256 + threadIdx.x;
    if (idx >= NN * F) return;
    int n = idx >> 5, ch = idx & 31;
    int t = ch >> 3, f = ch & 7;
    const float* xrow = xin + n * F + t * FT;
    const float* wB = preW + (t * 24 + 8) * 8 + f;
    float bv = 0.f;
#pragma unroll
    for (int k = 0; k < 8; k++) bv += xrow[k] * wB[k * 8];
    b16[idx] = f2bf_rne(bv);
}

// one wave per dst node; 32 lanes = channels, 2 halves alternate edges.
// h = b16_in[src] + sum_q dot2(eh2[q], wch[q]); compiler-scheduled unrolled loop.
// Barrier-free; fuses NEXT layer's node_pre into the epilogue (separate buffer).
__global__ __launch_bounds__(256) void gather_post(
        const float* __restrict__ xin,
        const unsigned short* __restrict__ b16_in,
        unsigned short* __restrict__ b16_out,  // may be nullptr (last layer)
        const float4* __restrict__ eh,         // [NE][2] fp16 eattr, CSR order
        const int* __restrict__ row_ptr, const int* __restrict__ cnt,
        const int* __restrict__ src_s,
        const float4* __restrict__ wchp_l,     // [32][2] this layer's packed wc16
        const float* __restrict__ abias_l,     // [32]
        const float* __restrict__ preW,        // [T,24,8]
        const float* __restrict__ postW, const float* __restrict__ postb,
        const float* __restrict__ linW, const float* __restrict__ linb,
        const float* __restrict__ preW_next,   // next layer's [T,24,8] or nullptr
        float* __restrict__ xout) {
    int tid = threadIdx.x;
    int wv = tid >> 6;
    int lane = tid & 63;
    int ch = lane & 31, half = lane >> 5;
    int n = blockIdx.x * 4 + wv;            // NN divisible by 4
    int t = ch >> 3, f = ch & 7;

    union { float4 f4[2]; h2 p[8]; } uw;
    uw.f4[0] = wchp_l[2 * ch];
    uw.f4[1] = wchp_l[2 * ch + 1];

    int rs = row_ptr[n], deg = cnt[n];
    int re = rs + deg;
    float S = 0.f, M = -3.4e38f;

#pragma unroll 4
    for (int i = rs + half; i < re; i += 2) {
        int s = src_s[i];
        float4 lo = eh[2 * (size_t)i];
        float4 hi = eh[2 * (size_t)i + 1];
        float h = __uint_as_float((unsigned)b16_in[s * F + ch] << 16);
        union { float4 f4; h2 p[4]; } ua, ub;
        ua.f4 = lo; ub.f4 = hi;
        h = dot2(ua.p[0], uw.p[0], h);
        h = dot2(ua.p[1], uw.p[1], h);
        h = dot2(ua.p[2], uw.p[2], h);
        h = dot2(ua.p[3], uw.p[3], h);
        h = dot2(ub.p[0], uw.p[4], h);
        h = dot2(ub.p[1], uw.p[5], h);
        h = dot2(ub.p[2], uw.p[6], h);
        h = dot2(ub.p[3], uw.p[7], h);
        S += h;
        M = fmaxf(M, h);
    }
    S += __shfl_xor(S, 32, 64);
    M = fmaxf(M, __shfl_xor(M, 32, 64));

    float xv = xin[(size_t)n * F + ch];
    // a_val = abias + preW_xi . xt  (own node, via shuffles of xv)
    float a_val = abias_l[ch];
#pragma unroll
    for (int j = 0; j < 8; j++)
        a_val += __shfl(xv, t * 8 + j, 64) * preW[(t * 24 + j) * 8 + f];

    float sum_h, mean_h, max_h;
    if (deg > 0) {
        sum_h = S + (float)deg * a_val;
        mean_h = sum_h / (float)deg;
        max_h = M + a_val;
    } else {
        sum_h = 0.f; mean_h = 0.f; max_h = 0.f;
    }

    // post-MLP per tower: u = postb + [xt|mean|sum|max] @ postW   (via shuffles)
    float u2 = postb[t * 8 + f];
#pragma unroll
    for (int kk = 0; kk < 8; kk++) {
        int sl = t * 8 + kk;
        u2 += __shfl(xv,     sl, 64) * postW[(t * 32 + 0 * 8 + kk) * 8 + f];
        u2 += __shfl(mean_h, sl, 64) * postW[(t * 32 + 1 * 8 + kk) * 8 + f];
        u2 += __shfl(sum_h,  sl, 64) * postW[(t * 32 + 2 * 8 + kk) * 8 + f];
        u2 += __shfl(max_h,  sl, 64) * postW[(t * 32 + 3 * 8 + kk) * 8 + f];
    }
    // final mixing linear + relu
    float y = linb[ch];
#pragma unroll
    for (int k = 0; k < 32; k++)
        y += __shfl(u2, k, 64) * linW[k * 32 + ch];
    y = fmaxf(y, 0.f);
    if (half == 0)
        xout[(size_t)n * F + ch] = y;

    // fused node_pre for next layer -> DIFFERENT buffer (no race)
    if (preW_next) {
        float bn = 0.f;
#pragma unroll
        for (int j = 0; j < 8; j++)
            bn += __shfl(y, t * 8 + j, 64) * preW_next[(t * 24 + 8 + j) * 8 + f];
        if (half == 0)
            b16_out[(size_t)n * F + ch] = f2bf_rne(bn);
    }
}

// ---------------- launch ----------------

extern "C" void kernel_launch(void* const* d_in, const int* in_sizes, int n_in,
                              void* d_out, int out_size, void* d_ws, size_t ws_size,
                              hipStream_t stream) {
    const float* x      = (const float*)d_in[0];
    const int*   ei     = (const int*)d_in[1];
    const float* eattr  = (const float*)d_in[2];
    const float* edge_W = (const float*)d_in[3];
    const float* edge_b = (const float*)d_in[4];
    const float* pre_W  = (const float*)d_in[5];
    const float* pre_b  = (const float*)d_in[6];
    const float* post_W = (const float*)d_in[7];
    const float* post_b = (const float*)d_in[8];
    const float* lin_W  = (const float*)d_in[9];
    const float* lin_b  = (const float*)d_in[10];
    float* out = (float*)d_out;

    const size_t NC = (size_t)NN * F;
    char* p = (char*)d_ws;
    float4* eh    = (float4*)p;        p += sizeof(float4) * 2 * (size_t)NE;  // 51.2 MB
    int* src_s    = (int*)p;           p += sizeof(int) * NE;
    int* cnt      = (int*)p;           p += sizeof(int) * NN;
    int* row_ptr  = (int*)p;           p += sizeof(int) * NN;
    int* cursor   = (int*)p;           p += sizeof(int) * NN;
    unsigned short* b16a = (unsigned short*)p;  p += sizeof(unsigned short) * NC;
    unsigned short* b16b = (unsigned short*)p;  p += sizeof(unsigned short) * NC;
    float* xb0    = (float*)p;         p += sizeof(float) * NC;
    float* xb1    = (float*)p;         p += sizeof(float) * NC;
    float4* wchp  = (float4*)p;        p += sizeof(float4) * 2 * NLAYERS * 32;
    float* abias  = (float*)p;         p += sizeof(float) * NLAYERS * 32;

    dim3 blk(256);
    int gN  = (NN + 255) / 256;
    int gE  = (NE + 255) / 256;
    int gNC = (NN * F + 255) / 256;
    int gG  = NN / 4;

    // CSR build + fp16 eattr permute + layer constants (once)
    hipLaunchKernelGGL(zero_cnt,     dim3(gN), blk, 0, stream, cnt);
    hipLaunchKernelGGL(count_kernel, dim3(gE), blk, 0, stream, ei, cnt);
    hipLaunchKernelGGL(scan_kernel,  dim3(1), dim3(1024), 0, stream, cnt, row_ptr, cursor);
    hipLaunchKernelGGL(build_kernel, dim3(gE), blk, 0, stream, ei, eattr,
                       cursor, src_s, eh);
    hipLaunchKernelGGL(layer_const,  dim3(1), blk, 0, stream,
                       edge_W, edge_b, pre_W, pre_b, wchp, abias);

    // layer 0's b16
    hipLaunchKernelGGL(node_pre, dim3(gNC), blk, 0, stream, x, pre_W, b16a);

    const float* xin = x;
    for (int l = 0; l < NLAYERS; l++) {
        const float* pW  = pre_W  + (size_t)l * T * 24 * FT;
        const float* poW = post_W + (size_t)l * T * 32 * FT;
        const float* pob = post_b + (size_t)l * T * FT;
        const float* lW  = lin_W  + (size_t)l * F * F;
        const float* lb  = lin_b  + (size_t)l * F;
        const float* pWn = (l + 1 < NLAYERS) ? (pre_W + (size_t)(l + 1) * T * 24 * FT)
                                             : nullptr;
        float* xout = (l == NLAYERS - 1) ? out : ((l & 1) ? xb1 : xb0);
        const unsigned short* bin  = (l & 1) ? b16b : b16a;
        unsigned short*       bout = (l & 1) ? b16a : b16b;

        hipLaunchKernelGGL(gather_post, dim3(gG), blk, 0, stream,
                           xin, bin, pWn ? bout : nullptr, eh, row_ptr, cnt, src_s,
                           wchp + (size_t)l * 64, abias + (size_t)l * 32,
                           pW, poW, pob, lW, lb, pWn, xout);
        xin = xout;
    }
}

// Round 10
// 756.440 us; speedup vs baseline: 1.1584x; 1.0156x over previous
//
#include <hip/hip_runtime.h>
#include <hip/hip_fp16.h>

#define NN 50000
#define NE 1600000
#define F 32
#define T 4
#define FT 8
#define ED 16
#define NLAYERS 5

typedef _Float16 h2 __attribute__((ext_vector_type(2)));

__device__ __forceinline__ float dot2(h2 a, h2 b, float c) {
#if __has_builtin(__builtin_amdgcn_fdot2)
    return __builtin_amdgcn_fdot2(a, b, c, false);
#else
    return c + (float)a.x * (float)b.x + (float)a.y * (float)b.y;
#endif
}

// ---------------- CSR build (once per call; edge_index constant across layers) ----

__global__ void zero_cnt(int* __restrict__ cnt) {
    int i = blockIdx.x * 256 + threadIdx.x;
    if (i < NN) cnt[i] = 0;
}

__global__ void count_kernel(const int* __restrict__ ei, int* __restrict__ cnt) {
    int e = blockIdx.x * 256 + threadIdx.x;
    if (e >= NE) return;
    atomicAdd(&cnt[ei[NE + e]], 1);
}

// one-block exclusive scan over cnt[NN] -> row_ptr, cursor (1024 threads)
__global__ void scan_kernel(const int* __restrict__ cnt, int* __restrict__ row_ptr,
                            int* __restrict__ cursor) {
    __shared__ int wsum[16];
    __shared__ int carry_s;
    int tid = threadIdx.x;
    int lane = tid & 63, wid = tid >> 6;
    if (tid == 0) carry_s = 0;
    __syncthreads();
    for (int base = 0; base < NN; base += 1024) {
        int i = base + tid;
        int v = (i < NN) ? cnt[i] : 0;
        int s = v;
#pragma unroll
        for (int off = 1; off < 64; off <<= 1) {
            int tt = __shfl_up(s, off, 64);
            if (lane >= off) s += tt;
        }
        __syncthreads();
        if (lane == 63) wsum[wid] = s;
        __syncthreads();
        if (wid == 0 && lane < 16) {
            int w = wsum[lane];
            int ws = w;
#pragma unroll
            for (int off = 1; off < 16; off <<= 1) {
                int tt = __shfl_up(ws, off, 16);
                if (lane >= off) ws += tt;
            }
            wsum[lane] = ws - w;
        }
        __syncthreads();
        int excl = carry_s + wsum[wid] + s - v;
        if (i < NN) { row_ptr[i] = excl; cursor[i] = excl; }
        __syncthreads();
        if (tid == 1023) carry_s += wsum[15] + s;
    }
}

// fused scatter: read eattr SEQUENTIALLY, compute CSR slot p, write src*32 + fp16 eattr.
__global__ void build_kernel(const int* __restrict__ ei,
                             const float* __restrict__ eattr,
                             int* __restrict__ cursor,
                             int* __restrict__ src_s,     // stores src*F (element offset)
                             float4* __restrict__ eh) {   // [NE][2] float4 (=16 half)
    int e = blockIdx.x * 256 + threadIdx.x;
    if (e >= NE) return;
    int src = ei[e];
    int dst = ei[NE + e];
    const float4* eap = (const float4*)(eattr + (size_t)e * ED);
    float4 v0 = eap[0], v1 = eap[1], v2 = eap[2], v3 = eap[3];
    union { __half hh[16]; float4 f4[2]; } u;
    u.hh[0]  = __float2half(v0.x); u.hh[1]  = __float2half(v0.y);
    u.hh[2]  = __float2half(v0.z); u.hh[3]  = __float2half(v0.w);
    u.hh[4]  = __float2half(v1.x); u.hh[5]  = __float2half(v1.y);
    u.hh[6]  = __float2half(v1.z); u.hh[7]  = __float2half(v1.w);
    u.hh[8]  = __float2half(v2.x); u.hh[9]  = __float2half(v2.y);
    u.hh[10] = __float2half(v2.z); u.hh[11] = __float2half(v2.w);
    u.hh[12] = __float2half(v3.x); u.hh[13] = __float2half(v3.y);
    u.hh[14] = __float2half(v3.z); u.hh[15] = __float2half(v3.w);
    int p = atomicAdd(&cursor[dst], 1);
    src_s[p] = src << 5;   // src * F
    eh[2 * (size_t)p]     = u.f4[0];
    eh[2 * (size_t)p + 1] = u.f4[1];
}

// per-layer constants: wchp[(l*32+ch)] = packed fp16 wc16 (16 halfs = 2 float4);
// abias[l*32+ch] = preb + ebias . preW_ee
__global__ void layer_const(const float* __restrict__ edge_W,  // [L,16,8]
                            const float* __restrict__ edge_b,  // [L,8]
                            const float* __restrict__ pre_W,   // [L,T,24,8]
                            const float* __restrict__ pre_b,   // [L,T,8]
                            float4* __restrict__ wchp,         // [L*32][2]
                            float* __restrict__ abias) {       // [L*32]
    int idx = threadIdx.x;
    if (idx >= NLAYERS * 32) return;
    int l = idx >> 5, ch = idx & 31;
    int t = ch >> 3, f = ch & 7;
    const float* eW = edge_W + (size_t)l * ED * FT;
    const float* eb = edge_b + (size_t)l * FT;
    const float* pW = pre_W + (size_t)l * T * 24 * FT;
    const float* pb = pre_b + (size_t)l * T * FT;
    float pj[8];
#pragma unroll
    for (int j = 0; j < 8; j++) pj[j] = pW[(t * 24 + 16 + j) * 8 + f];
    union { _Float16 hh[16]; float4 f4[2]; } u;
#pragma unroll
    for (int k = 0; k < 16; k++) {
        float s = 0.f;
#pragma unroll
        for (int j = 0; j < 8; j++) s += eW[k * 8 + j] * pj[j];
        u.hh[k] = (_Float16)s;
    }
    float c0 = pb[t * 8 + f];
#pragma unroll
    for (int j = 0; j < 8; j++) c0 += eb[j] * pj[j];
    wchp[2 * idx]     = u.f4[0];
    wchp[2 * idx + 1] = u.f4[1];
    abias[idx] = c0;
}

// ---------------- per-layer kernels ----------------

__device__ __forceinline__ unsigned short f2bf_rne(float v) {
    unsigned u = __float_as_uint(v);
    return (unsigned short)((u + 0x7FFFu + ((u >> 16) & 1u)) >> 16);
}

// b16[n][ch] = bf16(preW_xj . xt)   (layer 0 only; later layers fused in epilogue)
__global__ void node_pre(const float* __restrict__ xin,
                         const float* __restrict__ preW,
                         unsigned short* __restrict__ b16) {
    int idx = blockIdx.x * 256 + threadIdx.x;
    if (idx >= NN * F) return;
    int n = idx >> 5, ch = idx & 31;
    int t = ch >> 3, f = ch & 7;
    const float* xrow = xin + n * F + t * FT;
    const float* wB = preW + (t * 24 + 8) * 8 + f;
    float bv = 0.f;
#pragma unroll
    for (int k = 0; k < 8; k++) bv += xrow[k] * wB[k * 8];
    b16[idx] = f2bf_rne(bv);
}

__device__ __forceinline__ float edge_h(float4 lo, float4 hi, unsigned short b,
                                        const h2* wp) {
    union { float4 f4; h2 p[4]; } ua, ub;
    ua.f4 = lo; ub.f4 = hi;
    float h = __uint_as_float((unsigned)b << 16);
    h = dot2(ua.p[0], wp[0], h);
    h = dot2(ua.p[1], wp[1], h);
    h = dot2(ua.p[2], wp[2], h);
    h = dot2(ua.p[3], wp[3], h);
    h = dot2(ub.p[0], wp[4], h);
    h = dot2(ub.p[1], wp[5], h);
    h = dot2(ub.p[2], wp[6], h);
    h = dot2(ub.p[3], wp[7], h);
    return h;
}

// one wave per dst node; 32 lanes = channels, 2 halves alternate edges.
// Main loop: explicit 4-edge batches -> 4 independent src->b16 chains in flight.
// Barrier-free; fuses NEXT layer's node_pre into the epilogue (separate buffer).
__global__ __launch_bounds__(256) void gather_post(
        const float* __restrict__ xin,
        const unsigned short* __restrict__ b16_in,
        unsigned short* __restrict__ b16_out,  // may be nullptr (last layer)
        const float4* __restrict__ eh,         // [NE][2] fp16 eattr, CSR order
        const int* __restrict__ row_ptr, const int* __restrict__ cnt,
        const int* __restrict__ src_s,         // src*F per slot
        const float4* __restrict__ wchp_l,     // [32][2] this layer's packed wc16
        const float* __restrict__ abias_l,     // [32]
        const float* __restrict__ preW,        // [T,24,8]
        const float* __restrict__ postW, const float* __restrict__ postb,
        const float* __restrict__ linW, const float* __restrict__ linb,
        const float* __restrict__ preW_next,   // next layer's [T,24,8] or nullptr
        float* __restrict__ xout) {
    int tid = threadIdx.x;
    int wv = tid >> 6;
    int lane = tid & 63;
    int ch = lane & 31, half = lane >> 5;
    int n = blockIdx.x * 4 + wv;            // NN divisible by 4
    int t = ch >> 3, f = ch & 7;

    union { float4 f4[2]; h2 p[8]; } uw;
    uw.f4[0] = wchp_l[2 * ch];
    uw.f4[1] = wchp_l[2 * ch + 1];
    const unsigned short* bp = b16_in + ch;

    int rs = row_ptr[n], deg = cnt[n];
    int re = rs + deg;
    float S = 0.f, M = -3.4e38f;

    int i = rs + half;
    // main loop: 4 edges per lane per iteration, loads batched per class
#pragma unroll 1
    for (; i + 6 < re; i += 8) {
        int s0 = src_s[i];
        int s1 = src_s[i + 2];
        int s2 = src_s[i + 4];
        int s3 = src_s[i + 6];
        float4 l0 = eh[2 * (size_t)i],       h0 = eh[2 * (size_t)i + 1];
        float4 l1 = eh[2 * (size_t)(i + 2)], h1 = eh[2 * (size_t)(i + 2) + 1];
        float4 l2 = eh[2 * (size_t)(i + 4)], h2v = eh[2 * (size_t)(i + 4) + 1];
        float4 l3 = eh[2 * (size_t)(i + 6)], h3 = eh[2 * (size_t)(i + 6) + 1];
        unsigned short b0 = bp[s0];
        unsigned short b1 = bp[s1];
        unsigned short b2 = bp[s2];
        unsigned short b3 = bp[s3];
        float e0 = edge_h(l0, h0, b0, uw.p);
        float e1 = edge_h(l1, h1, b1, uw.p);
        float e2 = edge_h(l2, h2v, b2, uw.p);
        float e3 = edge_h(l3, h3, b3, uw.p);
        S += (e0 + e1) + (e2 + e3);
        M = fmaxf(M, fmaxf(fmaxf(e0, e1), fmaxf(e2, e3)));
    }
    // tail
    for (; i < re; i += 2) {
        int s = src_s[i];
        float4 lo = eh[2 * (size_t)i];
        float4 hi = eh[2 * (size_t)i + 1];
        float e0 = edge_h(lo, hi, bp[s], uw.p);
        S += e0;
        M = fmaxf(M, e0);
    }
    S += __shfl_xor(S, 32, 64);
    M = fmaxf(M, __shfl_xor(M, 32, 64));

    float xv = xin[(size_t)n * F + ch];
    // a_val = abias + preW_xi . xt  (own node, via shuffles of xv)
    float a_val = abias_l[ch];
#pragma unroll
    for (int j = 0; j < 8; j++)
        a_val += __shfl(xv, t * 8 + j, 64) * preW[(t * 24 + j) * 8 + f];

    float sum_h, mean_h, max_h;
    if (deg > 0) {
        sum_h = S + (float)deg * a_val;
        mean_h = sum_h / (float)deg;
        max_h = M + a_val;
    } else {
        sum_h = 0.f; mean_h = 0.f; max_h = 0.f;
    }

    // post-MLP per tower: u = postb + [xt|mean|sum|max] @ postW   (via shuffles)
    float u2 = postb[t * 8 + f];
#pragma unroll
    for (int kk = 0; kk < 8; kk++) {
        int sl = t * 8 + kk;
        u2 += __shfl(xv,     sl, 64) * postW[(t * 32 + 0 * 8 + kk) * 8 + f];
        u2 += __shfl(mean_h, sl, 64) * postW[(t * 32 + 1 * 8 + kk) * 8 + f];
        u2 += __shfl(sum_h,  sl, 64) * postW[(t * 32 + 2 * 8 + kk) * 8 + f];
        u2 += __shfl(max_h,  sl, 64) * postW[(t * 32 + 3 * 8 + kk) * 8 + f];
    }
    // final mixing linear + relu
    float y = linb[ch];
#pragma unroll
    for (int k = 0; k < 32; k++)
        y += __shfl(u2, k, 64) * linW[k * 32 + ch];
    y = fmaxf(y, 0.f);
    if (half == 0)
        xout[(size_t)n * F + ch] = y;

    // fused node_pre for next layer -> DIFFERENT buffer (no race)
    if (preW_next) {
        float bn = 0.f;
#pragma unroll
        for (int j = 0; j < 8; j++)
            bn += __shfl(y, t * 8 + j, 64) * preW_next[(t * 24 + 8 + j) * 8 + f];
        if (half == 0)
            b16_out[(size_t)n * F + ch] = f2bf_rne(bn);
    }
}

// ---------------- launch ----------------

extern "C" void kernel_launch(void* const* d_in, const int* in_sizes, int n_in,
                              void* d_out, int out_size, void* d_ws, size_t ws_size,
                              hipStream_t stream) {
    const float* x      = (const float*)d_in[0];
    const int*   ei     = (const int*)d_in[1];
    const float* eattr  = (const float*)d_in[2];
    const float* edge_W = (const float*)d_in[3];
    const float* edge_b = (const float*)d_in[4];
    const float* pre_W  = (const float*)d_in[5];
    const float* pre_b  = (const float*)d_in[6];
    const float* post_W = (const float*)d_in[7];
    const float* post_b = (const float*)d_in[8];
    const float* lin_W  = (const float*)d_in[9];
    const float* lin_b  = (const float*)d_in[10];
    float* out = (float*)d_out;

    const size_t NC = (size_t)NN * F;
    char* p = (char*)d_ws;
    float4* eh    = (float4*)p;        p += sizeof(float4) * 2 * (size_t)NE;  // 51.2 MB
    int* src_s    = (int*)p;           p += sizeof(int) * NE;
    int* cnt      = (int*)p;           p += sizeof(int) * NN;
    int* row_ptr  = (int*)p;           p += sizeof(int) * NN;
    int* cursor   = (int*)p;           p += sizeof(int) * NN;
    unsigned short* b16a = (unsigned short*)p;  p += sizeof(unsigned short) * NC;
    unsigned short* b16b = (unsigned short*)p;  p += sizeof(unsigned short) * NC;
    float* xb0    = (float*)p;         p += sizeof(float) * NC;
    float* xb1    = (float*)p;         p += sizeof(float) * NC;
    float4* wchp  = (float4*)p;        p += sizeof(float4) * 2 * NLAYERS * 32;
    float* abias  = (float*)p;         p += sizeof(float) * NLAYERS * 32;

    dim3 blk(256);
    int gN  = (NN + 255) / 256;
    int gE  = (NE + 255) / 256;
    int gNC = (NN * F + 255) / 256;
    int gG  = NN / 4;

    // CSR build + fp16 eattr permute + layer constants (once)
    hipLaunchKernelGGL(zero_cnt,     dim3(gN), blk, 0, stream, cnt);
    hipLaunchKernelGGL(count_kernel, dim3(gE), blk, 0, stream, ei, cnt);
    hipLaunchKernelGGL(scan_kernel,  dim3(1), dim3(1024), 0, stream, cnt, row_ptr, cursor);
    hipLaunchKernelGGL(build_kernel, dim3(gE), blk, 0, stream, ei, eattr,
                       cursor, src_s, eh);
    hipLaunchKernelGGL(layer_const,  dim3(1), blk, 0, stream,
                       edge_W, edge_b, pre_W, pre_b, wchp, abias);

    // layer 0's b16
    hipLaunchKernelGGL(node_pre, dim3(gNC), blk, 0, stream, x, pre_W, b16a);

    const float* xin = x;
    for (int l = 0; l < NLAYERS; l++) {
        const float* pW  = pre_W  + (size_t)l * T * 24 * FT;
        const float* poW = post_W + (size_t)l * T * 32 * FT;
        const float* pob = post_b + (size_t)l * T * FT;
        const float* lW  = lin_W  + (size_t)l * F * F;
        const float* lb  = lin_b  + (size_t)l * F;
        const float* pWn = (l + 1 < NLAYERS) ? (pre_W + (size_t)(l + 1) * T * 24 * FT)
                                             : nullptr;
        float* xout = (l == NLAYERS - 1) ? out : ((l & 1) ? xb1 : xb0);
        const unsigned short* bin  = (l & 1) ? b16b : b16a;
        unsigned short*       bout = (l & 1) ? b16a : b16b;

        hipLaunchKernelGGL(gather_post, dim3(gG), blk, 0, stream,
                           xin, bin, pWn ? bout : nullptr, eh, row_ptr, cnt, src_s,
                           wchp + (size_t)l * 64, abias + (size_t)l * 32,
                           pW, poW, pob, lW, lb, pWn, xout);
        xin = xout;
    }
}